// Round 5
// baseline (86.545 us; speedup 1.0000x reference)
//
#include <hip/hip_runtime.h>
#include <math.h>

#define NTOK 16384   // B*S
#define DDIM 2048
#define NEXP 64
#define MTILE 16     // tokens per block
#define KSUP 128     // k per LDS superstep
#define NSUP 16      // DDIM / KSUP

typedef __attribute__((ext_vector_type(8))) short bf16x8;
typedef __attribute__((ext_vector_type(4))) float f32x4;

// ---- 3-way bf16 split: x ~= h + m + l, residual <= 2^-27 |x| ----
__device__ __forceinline__ unsigned short f2bf(float f) {
    unsigned int u = __builtin_bit_cast(unsigned int, f);
    u += 0x7fffu + ((u >> 16) & 1u);          // RNE to bf16
    return (unsigned short)(u >> 16);
}
__device__ __forceinline__ float bf2f(unsigned short s) {
    return __builtin_bit_cast(float, ((unsigned int)s) << 16);
}
__device__ __forceinline__ void split3(float x, unsigned short &h,
                                       unsigned short &m, unsigned short &l) {
    h = f2bf(x);
    float r1 = x - bf2f(h);    // exact (Sterbenz)
    m = f2bf(r1);
    float r2 = r1 - bf2f(m);   // exact
    l = f2bf(r2);
}

// ---- pack gate_w into B-fragment layout: wp[(eg*64+ks)*3*512 + p*512 + lane*8]
__global__ void k_wpack(const float* __restrict__ gw, unsigned short* __restrict__ wp) {
    int idx = blockIdx.x * 256 + threadIdx.x;   // 16384 threads
    int lane = idx & 63;
    int ks   = (idx >> 6) & 63;                 // global k-step (32 k each)
    int eg   = idx >> 12;                       // expert group 0..3
    int e  = eg * 16 + (lane & 15);
    int k0 = ks * 32 + (lane >> 4) * 8;
    const float* src = gw + (size_t)e * DDIM + k0;
    union { unsigned short s[8]; uint4 v; } H, M, L;
    #pragma unroll
    for (int j = 0; j < 8; ++j) split3(src[j], H.s[j], M.s[j], L.s[j]);
    size_t fb = (size_t)(eg * 64 + ks) * 1536 + lane * 8;   // shorts
    *(uint4*)(wp + fb)        = H.v;
    *(uint4*)(wp + fb + 512)  = M.v;
    *(uint4*)(wp + fb + 1024) = L.v;
}

// stage 4 floats (chunk c of this thread's row) into swizzled LDS slab.
// slab layout: [3 part][16 row][16 slot * 16B], slot XOR-swizzled by row.
__device__ __forceinline__ void stage4(char* bb, int srow, int subk, int c, float4 v) {
    unsigned short h0,h1,h2,h3, m0,m1,m2,m3, l0,l1,l2,l3;
    split3(v.x, h0, m0, l0);
    split3(v.y, h1, m1, l1);
    split3(v.z, h2, m2, l2);
    split3(v.w, h3, m3, l3);
    char* pb = bb + srow * 256 + (((c * 8 + (subk >> 1)) ^ srow) << 4)
                  + (subk & 1) * 8;
    *(uint2*)(pb)        = make_uint2((unsigned)h0 | ((unsigned)h1 << 16),
                                      (unsigned)h2 | ((unsigned)h3 << 16));
    *(uint2*)(pb + 4096) = make_uint2((unsigned)m0 | ((unsigned)m1 << 16),
                                      (unsigned)m2 | ((unsigned)m3 << 16));
    *(uint2*)(pb + 8192) = make_uint2((unsigned)l0 | ((unsigned)l1 << 16),
                                      (unsigned)l2 | ((unsigned)l3 << 16));
}

// ---- main: GEMM (6-pass split-bf16 MFMA) + softmax + top2 + aux, fused ----
__global__ __launch_bounds__(256, 4)
void k_main(const float* __restrict__ x, const unsigned short* __restrict__ wp,
            float* __restrict__ out, float* __restrict__ gcnt,
            float* __restrict__ gP, float* __restrict__ gz) {
    // Double-buffered A slabs; ONE barrier per superstep:
    // iter ss: barrier; stage buf[(ss+1)&1]; compute buf[ss&1].
    __shared__ __align__(16) char As[2][12288];
    __shared__ float Lg[MTILE][65];
    __shared__ float Ps[NEXP], Cnt[NEXP], Zs;

    const int tid = threadIdx.x;
    if (tid < NEXP) { Ps[tid] = 0.f; Cnt[tid] = 0.f; }
    if (tid == 0) Zs = 0.f;

    const int tok0 = blockIdx.x * MTILE;
    const int lane = tid & 63;
    const int eg   = __builtin_amdgcn_readfirstlane(tid >> 6);   // wave = expert group
    const int tau  = lane & 15;
    const int kappa = lane >> 4;

    // staging map: thread owns row tid>>4, two 4-float chunks at k=subk*4, +64
    const int srow = tid >> 4;
    const int subk = tid & 15;
    const float* xb = x + (size_t)(tok0 + srow) * DDIM + subk * 4;

    // prologue: stage superstep 0, prefetch superstep 1
    float4 xc0 = *(const float4*)(xb);
    float4 xc1 = *(const float4*)(xb + 64);
    stage4(As[0], srow, subk, 0, xc0);
    stage4(As[0], srow, subk, 1, xc1);
    xc0 = *(const float4*)(xb + 128);
    xc1 = *(const float4*)(xb + 128 + 64);

    // W fragment rolling register prefetch, 2 ksteps deep (wf[ks&1])
    const unsigned short* wpe = wp + (size_t)eg * 64 * 1536 + lane * 8;
    bf16x8 wf[2][3];
    #pragma unroll
    for (int p = 0; p < 3; ++p) wf[0][p] = *(const bf16x8*)(wpe + p * 512);
    #pragma unroll
    for (int p = 0; p < 3; ++p) wf[1][p] = *(const bf16x8*)(wpe + 1536 + p * 512);

    f32x4 acc = {0.f, 0.f, 0.f, 0.f};

    for (int ss = 0; ss < NSUP; ++ss) {
        __syncthreads();
        // ---- stage next superstep into the other buffer, prefetch ss+2
        if (ss + 1 < NSUP) {
            char* nb = As[(ss + 1) & 1];
            stage4(nb, srow, subk, 0, xc0);
            stage4(nb, srow, subk, 1, xc1);
            int nss = (ss + 2) & (NSUP - 1);
            xc0 = *(const float4*)(xb + nss * KSUP);
            xc1 = *(const float4*)(xb + nss * KSUP + 64);
        }
        // ---- 4 MFMA k-steps on current buffer; W regs reloaded 2 ahead
        const char* bb = As[ss & 1];
        #pragma unroll
        for (int ks = 0; ks < 4; ++ks) {
            const char* p0 = bb + tau * 256 + ((((ks << 2) + kappa) ^ tau) << 4);
            bf16x8 Ah = *(const bf16x8*)(p0);
            bf16x8 Am = *(const bf16x8*)(p0 + 4096);
            bf16x8 Al = *(const bf16x8*)(p0 + 8192);
            bf16x8 Bh = wf[ks & 1][0];
            bf16x8 Bm = wf[ks & 1][1];
            bf16x8 Bl = wf[ks & 1][2];

            acc = __builtin_amdgcn_mfma_f32_16x16x32_bf16(Ah, Bh, acc, 0, 0, 0);
            acc = __builtin_amdgcn_mfma_f32_16x16x32_bf16(Ah, Bm, acc, 0, 0, 0);
            acc = __builtin_amdgcn_mfma_f32_16x16x32_bf16(Am, Bh, acc, 0, 0, 0);
            acc = __builtin_amdgcn_mfma_f32_16x16x32_bf16(Ah, Bl, acc, 0, 0, 0);
            acc = __builtin_amdgcn_mfma_f32_16x16x32_bf16(Al, Bh, acc, 0, 0, 0);
            acc = __builtin_amdgcn_mfma_f32_16x16x32_bf16(Am, Bm, acc, 0, 0, 0);

            int nk = ((ss << 2) + ks + 2) & 63;   // wraps harmlessly on last ss
            #pragma unroll
            for (int pI = 0; pI < 3; ++pI)
                wf[ks & 1][pI] = *(const bf16x8*)(wpe + (size_t)nk * 1536 + pI * 512);
        }
    }

    // ---- logits to LDS: C/D layout col=lane&15 (expert), row=(lane>>4)*4+j
    #pragma unroll
    for (int j = 0; j < 4; ++j)
        Lg[kappa * 4 + j][eg * 16 + tau] = acc[j];
    __syncthreads();

    // ---- phase 2: softmax / top-2 / aux. lane = expert, each wave 4 tokens.
    float Pacc = 0.f, zacc = 0.f;
    const int wv = tid >> 6;
    for (int i = 0; i < 4; ++i) {
        int t = wv * 4 + i;
        float l = Lg[t][lane];
        float mx = l;
        #pragma unroll
        for (int off = 32; off > 0; off >>= 1) mx = fmaxf(mx, __shfl_xor(mx, off));
        float s = expf(l - mx);
        float sum = s;
        #pragma unroll
        for (int off = 32; off > 0; off >>= 1) sum += __shfl_xor(sum, off);
        Pacc += s / sum;

        unsigned long long b1 = __ballot(l == mx);
        int i1 = __ffsll(b1) - 1;              // lowest index on ties
        float l2 = (lane == i1) ? -INFINITY : l;
        float m2 = l2;
        #pragma unroll
        for (int off = 32; off > 0; off >>= 1) m2 = fmaxf(m2, __shfl_xor(m2, off));
        unsigned long long b2 = __ballot(l2 == m2);
        int i2 = __ffsll(b2) - 1;

        if (lane == 0) {
            float s2  = expf(m2 - mx);
            float inv = 1.f / (1.f + s2);
            int gt = tok0 + t;
            ((float2*)out)[gt]              = make_float2((float)i1, (float)i2);
            ((float2*)(out + 2 * NTOK))[gt] = make_float2(inv, s2 * inv);
            atomicAdd(&Cnt[i1], 1.f);
            atomicAdd(&Cnt[i2], 1.f);
            float lse = mx + logf(sum);
            zacc += lse * lse;
        }
    }
    atomicAdd(&Ps[lane], Pacc);
    if (lane == 0) atomicAdd(&Zs, zacc);
    __syncthreads();

    if (tid < NEXP) {
        atomicAdd(&gcnt[tid], Cnt[tid]);
        atomicAdd(&gP[tid],   Ps[tid]);
    }
    if (tid == 0) atomicAdd(gz, Zs);
}

__global__ void k_final(const float* __restrict__ ws, float* __restrict__ out) {
    int lane = threadIdx.x;  // 64 threads
    float v = ws[lane] * ws[64 + lane];   // cnt_e * Psum_e
    #pragma unroll
    for (int off = 32; off > 0; off >>= 1) v += __shfl_xor(v, off);
    if (lane == 0) {
        float bal = 64.f * v / (32768.f * 16384.f);
        float z   = ws[128] / 16384.f;
        out[4 * NTOK] = 0.01f * bal + 0.001f * z;
    }
}

extern "C" void kernel_launch(void* const* d_in, const int* in_sizes, int n_in,
                              void* d_out, int out_size, void* d_ws, size_t ws_size,
                              hipStream_t stream) {
    const float* x  = (const float*)d_in[0];
    const float* gw = (const float*)d_in[1];
    float* out = (float*)d_out;
    float* wsf = (float*)d_ws;
    unsigned short* wp = (unsigned short*)((char*)d_ws + 1024);

    hipMemsetAsync(d_ws, 0, 516, stream);   // zero aux accumulators
    k_wpack<<<64, 256, 0, stream>>>(gw, wp);
    k_main<<<NTOK / MTILE, 256, 0, stream>>>(x, wp, out, wsf, wsf + 64, wsf + 128);
    k_final<<<1, 64, 0, stream>>>(wsf, out);
}

// Round 6
// 84.911 us; speedup vs baseline: 1.0192x; 1.0192x over previous
//
#include <hip/hip_runtime.h>
#include <math.h>

#define NTOK 16384   // B*S
#define DDIM 2048
#define NEXP 64
#define NKQ 8        // K split into 8 slices
#define KSLICE 256   // k per slice (8 ksteps of 32)
#define TPB 128      // tokens per gemm block (8 waves x 16)

typedef __attribute__((ext_vector_type(8))) short bf16x8;
typedef __attribute__((ext_vector_type(4))) float f32x4;

// ws layout (bytes):
//   [0, 516)          aux accumulators: cnt[64], Psum[64], zsum (zeroed per call)
//   [1024, 787456)    wp: packed W fragments [4 eg][64 ks][3 part][512 shorts]
//   [1MB, 1MB+32MB)   partial logits: [8 kq][16384 tok][64 exp] fp32

// ---- 3-way bf16 split: x ~= h + m + l, residual <= 2^-27 |x| ----
__device__ __forceinline__ unsigned short f2bf(float f) {
    unsigned int u = __builtin_bit_cast(unsigned int, f);
    u += 0x7fffu + ((u >> 16) & 1u);          // RNE to bf16
    return (unsigned short)(u >> 16);
}
__device__ __forceinline__ float bf2f(unsigned short s) {
    return __builtin_bit_cast(float, ((unsigned int)s) << 16);
}
__device__ __forceinline__ void split3(float x, unsigned short &h,
                                       unsigned short &m, unsigned short &l) {
    h = f2bf(x);
    float r1 = x - bf2f(h);    // exact (Sterbenz)
    m = f2bf(r1);
    float r2 = r1 - bf2f(m);   // exact
    l = f2bf(r2);
}

// ---- pack gate_w into B-fragment layout (validated, unchanged) ----
__global__ void k_wpack(const float* __restrict__ gw, unsigned short* __restrict__ wp) {
    int idx = blockIdx.x * 256 + threadIdx.x;   // 16384 threads
    int lane = idx & 63;
    int ks   = (idx >> 6) & 63;                 // global k-step (32 k each)
    int eg   = idx >> 12;                       // expert group 0..3
    int e  = eg * 16 + (lane & 15);
    int k0 = ks * 32 + (lane >> 4) * 8;
    const float* src = gw + (size_t)e * DDIM + k0;
    union { unsigned short s[8]; uint4 v; } H, M, L;
    #pragma unroll
    for (int j = 0; j < 8; ++j) split3(src[j], H.s[j], M.s[j], L.s[j]);
    size_t fb = (size_t)(eg * 64 + ks) * 1536 + lane * 8;   // shorts
    *(uint4*)(wp + fb)        = H.v;
    *(uint4*)(wp + fb + 512)  = M.v;
    *(uint4*)(wp + fb + 1024) = L.v;
}

// ---- phase 1: barrier-free K-sliced GEMM, W in LDS, x streamed to registers
__global__ __launch_bounds__(512, 2)
void k_gemm(const float* __restrict__ x, const unsigned short* __restrict__ wp,
            float* __restrict__ part) {
    // Ws: [4 eg][8 ksl][3 part][1024 B] — same fragment layout as wp slice
    __shared__ __align__(16) char Ws[98304];

    const int tid  = threadIdx.x;
    const int kq   = blockIdx.x & 7;            // k slice
    const int tok0 = (blockIdx.x >> 3) * TPB;   // token chunk base

    const int lane = tid & 63;
    const int wv   = tid >> 6;                  // 0..7: wave owns 16 tokens
    const int tau  = lane & 15;
    const int kap  = lane >> 4;

    // ---- x prefetch prologue (4-kstep ring): this lane's row/k-position
    const float* xb = x + (size_t)(tok0 + wv * 16 + tau) * DDIM
                        + kq * KSLICE + kap * 8;
    float4 xf[4][2];
    #pragma unroll
    for (int i = 0; i < 4; ++i) {
        xf[i][0] = *(const float4*)(xb + i * 32);
        xf[i][1] = *(const float4*)(xb + i * 32 + 4);
    }

    // ---- stage this block's W slice into LDS (contiguous 24 KB per eg)
    {
        const char* wpb = (const char*)wp;
        #pragma unroll
        for (int eg = 0; eg < 4; ++eg) {
            const char* s = wpb + (size_t)(eg * 64 + kq * 8) * 3072;
            char* d = Ws + eg * 24576;
            #pragma unroll
            for (int r = 0; r < 3; ++r) {
                int o = (r * 512 + tid) * 16;
                *(uint4*)(d + o) = *(const uint4*)(s + o);
            }
        }
    }
    __syncthreads();   // the ONLY barrier; LDS read-only afterwards

    f32x4 acc[4];
    #pragma unroll
    for (int eg = 0; eg < 4; ++eg) acc[eg] = (f32x4){0.f, 0.f, 0.f, 0.f};

    #pragma unroll
    for (int ks = 0; ks < 8; ++ks) {
        // split3 the current x fragment (8 consecutive k)
        float4 a = xf[ks & 3][0], b = xf[ks & 3][1];
        union U8 { unsigned short s[8]; bf16x8 v; };
        U8 Ah, Am, Al;
        float in[8] = {a.x, a.y, a.z, a.w, b.x, b.y, b.z, b.w};
        #pragma unroll
        for (int j = 0; j < 8; ++j) split3(in[j], Ah.s[j], Am.s[j], Al.s[j]);

        // refill ring for kstep ks+4
        if (ks < 4) {
            xf[ks & 3][0] = *(const float4*)(xb + (ks + 4) * 32);
            xf[ks & 3][1] = *(const float4*)(xb + (ks + 4) * 32 + 4);
        }

        #pragma unroll
        for (int eg = 0; eg < 4; ++eg) {
            const char* wb = Ws + eg * 24576 + ks * 3072 + lane * 16;
            bf16x8 Bh = *(const bf16x8*)(wb);
            bf16x8 Bm = *(const bf16x8*)(wb + 1024);
            bf16x8 Bl = *(const bf16x8*)(wb + 2048);
            acc[eg] = __builtin_amdgcn_mfma_f32_16x16x32_bf16(Ah.v, Bh, acc[eg], 0, 0, 0);
            acc[eg] = __builtin_amdgcn_mfma_f32_16x16x32_bf16(Ah.v, Bm, acc[eg], 0, 0, 0);
            acc[eg] = __builtin_amdgcn_mfma_f32_16x16x32_bf16(Am.v, Bh, acc[eg], 0, 0, 0);
            acc[eg] = __builtin_amdgcn_mfma_f32_16x16x32_bf16(Ah.v, Bl, acc[eg], 0, 0, 0);
            acc[eg] = __builtin_amdgcn_mfma_f32_16x16x32_bf16(Al.v, Bh, acc[eg], 0, 0, 0);
            acc[eg] = __builtin_amdgcn_mfma_f32_16x16x32_bf16(Am.v, Bm, acc[eg], 0, 0, 0);
        }
    }

    // ---- store partials: part[kq][tok][e]; C/D: col=tau(exp), row=kap*4+j(tok)
    float* pb = part + ((size_t)kq * NTOK + tok0 + wv * 16) * 64;
    #pragma unroll
    for (int eg = 0; eg < 4; ++eg)
        #pragma unroll
        for (int j = 0; j < 4; ++j)
            pb[(kap * 4 + j) * 64 + eg * 16 + tau] = acc[eg][j];
}

// ---- phase 2: deterministic K-reduction + softmax / top-2 / aux ----
__global__ __launch_bounds__(256)
void k_reduce(const float* __restrict__ part, float* __restrict__ out,
              float* __restrict__ gcnt, float* __restrict__ gP,
              float* __restrict__ gz) {
    __shared__ float Ps[NEXP], Cnt[NEXP], Zs;
    const int tid = threadIdx.x;
    if (tid < NEXP) { Ps[tid] = 0.f; Cnt[tid] = 0.f; }
    if (tid == 0) Zs = 0.f;
    __syncthreads();   // init must complete before any wave's atomicAdd

    const int lane = tid & 63;
    const int wv   = tid >> 6;
    const int t0   = blockIdx.x * 16 + wv * 4;   // 4 tokens per wave

    // load all partials for 4 tokens (fully static indexing)
    float v[4][8];
    #pragma unroll
    for (int i = 0; i < 4; ++i)
        #pragma unroll
        for (int q = 0; q < 8; ++q)
            v[i][q] = part[((size_t)q * NTOK + t0 + i) * 64 + lane];

    float Pacc = 0.f, zacc = 0.f;
    #pragma unroll
    for (int i = 0; i < 4; ++i) {
        // fixed-order pairwise sum over the 8 k-slices (deterministic)
        float l = ((v[i][0] + v[i][1]) + (v[i][2] + v[i][3]))
                + ((v[i][4] + v[i][5]) + (v[i][6] + v[i][7]));
        float mx = l;
        #pragma unroll
        for (int off = 32; off > 0; off >>= 1) mx = fmaxf(mx, __shfl_xor(mx, off));
        float s = expf(l - mx);
        float sum = s;
        #pragma unroll
        for (int off = 32; off > 0; off >>= 1) sum += __shfl_xor(sum, off);
        Pacc += s / sum;

        unsigned long long b1 = __ballot(l == mx);
        int i1 = __ffsll(b1) - 1;              // lowest index on ties
        float l2 = (lane == i1) ? -INFINITY : l;
        float m2 = l2;
        #pragma unroll
        for (int off = 32; off > 0; off >>= 1) m2 = fmaxf(m2, __shfl_xor(m2, off));
        unsigned long long b2 = __ballot(l2 == m2);
        int i2 = __ffsll(b2) - 1;

        if (lane == 0) {
            float s2  = expf(m2 - mx);
            float inv = 1.f / (1.f + s2);
            int gt = t0 + i;
            ((float2*)out)[gt]              = make_float2((float)i1, (float)i2);
            ((float2*)(out + 2 * NTOK))[gt] = make_float2(inv, s2 * inv);
            atomicAdd(&Cnt[i1], 1.f);
            atomicAdd(&Cnt[i2], 1.f);
            float lse = mx + logf(sum);
            zacc += lse * lse;
        }
    }
    atomicAdd(&Ps[lane], Pacc);
    if (lane == 0) atomicAdd(&Zs, zacc);
    __syncthreads();

    if (tid < NEXP) {
        atomicAdd(&gcnt[tid], Cnt[tid]);
        atomicAdd(&gP[tid],   Ps[tid]);
    }
    if (tid == 0) atomicAdd(gz, Zs);
}

__global__ void k_final(const float* __restrict__ ws, float* __restrict__ out) {
    int lane = threadIdx.x;  // 64 threads
    float v = ws[lane] * ws[64 + lane];   // cnt_e * Psum_e
    #pragma unroll
    for (int off = 32; off > 0; off >>= 1) v += __shfl_xor(v, off);
    if (lane == 0) {
        float bal = 64.f * v / (32768.f * 16384.f);
        float z   = ws[128] / 16384.f;
        out[4 * NTOK] = 0.01f * bal + 0.001f * z;
    }
}

extern "C" void kernel_launch(void* const* d_in, const int* in_sizes, int n_in,
                              void* d_out, int out_size, void* d_ws, size_t ws_size,
                              hipStream_t stream) {
    const float* x  = (const float*)d_in[0];
    const float* gw = (const float*)d_in[1];
    float* out = (float*)d_out;
    float* wsf = (float*)d_ws;
    unsigned short* wp = (unsigned short*)((char*)d_ws + 1024);
    float* part = (float*)((char*)d_ws + (1 << 20));

    hipMemsetAsync(d_ws, 0, 516, stream);   // zero aux accumulators
    k_wpack<<<64, 256, 0, stream>>>(gw, wp);
    k_gemm<<<NKQ * (NTOK / TPB), 512, 0, stream>>>(x, wp, part);
    k_reduce<<<NTOK / 16, 256, 0, stream>>>(part, out, wsf, wsf + 64, wsf + 128);
    k_final<<<1, 64, 0, stream>>>(wsf, out);
}